// Round 6
// baseline (4219.456 us; speedup 1.0000x reference)
//
#include <hip/hip_runtime.h>
#include <hip/hip_bf16.h>
#include <stdint.h>

#define GRIDN 48
#define F 2304
#define C 128
#define H 8
#define DH 16
#define NB 2          // batch (meshes)
#define WID 256
#define NLV 49        // BFS levels for GRID=48, anchor at (24,24)

#define NFB 144       // flood blocks (72 per mesh) -- all co-resident on 256 CUs
#define NFBM 72       // flood blocks per mesh
#define NFT 1024      // threads per flood block (16 waves)
#define NQI 32        // owned sorted positions per block (stride NFBM)
#define MAXRING 96    // max BFS ring size (94) padded

typedef __hip_bfloat16 bf16;

__device__ __forceinline__ float b2f(bf16 v) { return __bfloat162float(v); }

// ---------------------------------------------------------------- K-1: input dtype detector
__global__ void k_detect(const void* __restrict__ x, int* __restrict__ flag) {
    __shared__ int bad;
    if (threadIdx.x == 0) bad = 0;
    __syncthreads();
    const bf16* xb = (const bf16*)x;
    int insane = 0;
    #pragma unroll
    for (int i = 0; i < 8; ++i) {
        float v = b2f(xb[threadIdx.x * 8 + i]);
        if (!(fabsf(v) < 1e10f)) insane = 1;
    }
    if (insane) atomicOr(&bad, 1);
    __syncthreads();
    if (threadIdx.x == 0) *flag = bad;
}

// ---------------------------------------------------------------- K0: ring permutation tables
__global__ void k_perm(int* __restrict__ permIdx, int* __restrict__ invPerm,
                       int* __restrict__ startOfPos, int* __restrict__ ringStart,
                       int* __restrict__ gcount) {
    __shared__ int cnt[NLV], start[NLV], rs0[NLV];
    int t = threadIdx.x;
    if (t < NLV) cnt[t] = 0;
    if (t == 0) *gcount = 0;
    __syncthreads();
    for (int f = t; f < F; f += 256) {
        int d = abs(f / GRIDN - GRIDN / 2) + abs(f % GRIDN - GRIDN / 2);
        atomicAdd(&cnt[d], 1);
    }
    __syncthreads();
    if (t == 0) {
        int s = 0;
        for (int l = 0; l < NLV; ++l) { start[l] = s; rs0[l] = s; ringStart[l] = s; s += cnt[l]; }
        ringStart[NLV] = s;
    }
    __syncthreads();
    for (int f = t; f < F; f += 256) {
        int d = abs(f / GRIDN - GRIDN / 2) + abs(f % GRIDN - GRIDN / 2);
        int p = atomicAdd(&start[d], 1);
        permIdx[f] = p;
        invPerm[p] = f;
        startOfPos[p] = rs0[d];
    }
}

// ---------------------------------------------------------------- K0b: weights -> fp32
struct WSeg { const void* src; int off; int cnt; };
struct WSegs { WSeg s[14]; };

__global__ void k_convert(WSegs segs, const int* __restrict__ flag,
                          float* __restrict__ dst, int total) {
    int i = blockIdx.x * blockDim.x + threadIdx.x;
    if (i >= total) return;
    bool f32 = (*flag != 0);
    #pragma unroll 1
    for (int j = 0; j < 14; ++j) {
        int off = segs.s[j].off, cnt = segs.s[j].cnt;
        if (i >= off && i < off + cnt) {
            int k = i - off;
            dst[i] = f32 ? ((const float*)segs.s[j].src)[k]
                         : b2f(((const bf16*)segs.s[j].src)[k]);
            return;
        }
    }
}

// ---------------------------------------------------------------- K1: x[B,C,F] -> cur[B,F,C]
__global__ void k_transpose_in(const void* __restrict__ x, const int* __restrict__ flag,
                               float* __restrict__ cur) {
    __shared__ float tile[32][33];
    bool f32 = (*flag != 0);
    int b = blockIdx.z;
    int f0 = blockIdx.x * 32, c0 = blockIdx.y * 32;
    int tx = threadIdx.x, ty = threadIdx.y;
    #pragma unroll
    for (int i = 0; i < 4; ++i) {
        int c = c0 + ty + i * 8;
        size_t idx = ((size_t)b * C + c) * F + f0 + tx;
        tile[ty + i * 8][tx] = f32 ? ((const float*)x)[idx] : b2f(((const bf16*)x)[idx]);
    }
    __syncthreads();
    #pragma unroll
    for (int i = 0; i < 4; ++i) {
        int f = f0 + ty + i * 8;
        cur[((size_t)b * F + f) * C + c0 + tx] = tile[tx][ty + i * 8];
    }
}

// ---------------------------------------------------------------- K2: projections; khT/vhT [mesh][c][F] ring-permuted
__global__ __launch_bounds__(128) void k_proj_init(
        const float* __restrict__ cur, const int* __restrict__ permIdx,
        const float* __restrict__ Wq, const float* __restrict__ Wk, const float* __restrict__ Wv,
        float* __restrict__ qh, float* __restrict__ khT, float* __restrict__ vhT) {
    __shared__ float rows[8][C];
    int r0 = blockIdx.x * 8;
    int tid = threadIdx.x;
    #pragma unroll
    for (int r = 0; r < 8; ++r) rows[r][tid] = cur[(size_t)(r0 + r) * C + tid];
    __syncthreads();
    float aq[8], ak[8], av[8];
    #pragma unroll
    for (int r = 0; r < 8; ++r) { aq[r] = 0.f; ak[r] = 0.f; av[r] = 0.f; }
    for (int k = 0; k < C; ++k) {
        float wq = Wq[k * C + tid];
        float wk = Wk[k * C + tid];
        float wv = Wv[k * C + tid];
        #pragma unroll
        for (int r = 0; r < 8; ++r) {
            float xv = rows[r][k];
            aq[r] = fmaf(xv, wq, aq[r]);
            ak[r] = fmaf(xv, wk, ak[r]);
            av[r] = fmaf(xv, wv, av[r]);
        }
    }
    const float scale = 0.25f;
    #pragma unroll
    for (int r = 0; r < 8; ++r) {
        int grow = r0 + r;
        int mesh = grow / F, face = grow % F;
        int p = permIdx[face];
        qh[(size_t)grow * C + tid] = aq[r] * scale;
        khT[((size_t)mesh * C + tid) * F + p] = ak[r];
        vhT[((size_t)mesh * C + tid) * F + p] = av[r];
    }
}

// ---------------------------------------------------------------- K3a: suffix attention (initial K/V), 4 queries/block
__global__ __launch_bounds__(256) void k_suffix(
        const int* __restrict__ invPerm, const int* __restrict__ startOfPos,
        const float* __restrict__ qh_all,
        const float* __restrict__ khT, const float* __restrict__ vhT,
        float* __restrict__ sufM, float* __restrict__ sufL, float* __restrict__ sufA) {
    int bx = blockIdx.x;
    int mesh = bx & 1;
    int p0 = (bx >> 1) * 4;
    int tid = threadIdx.x;
    __shared__ float sQh[4][C];
    __shared__ int sFace[4], sStart[4];
    if (tid < 4) {
        sFace[tid] = invPerm[p0 + tid];
        sStart[tid] = startOfPos[p0 + tid];
    }
    __syncthreads();
    {
        int j = tid >> 7, ch = tid & 127;
        sQh[j][ch]     = qh_all[((size_t)mesh * F + sFace[j]) * C + ch];
        sQh[j + 2][ch] = qh_all[((size_t)mesh * F + sFace[j + 2]) * C + ch];
    }
    __syncthreads();
    int head = tid >> 5, sub = tid & 31;
    float q[4][DH];
    #pragma unroll
    for (int j = 0; j < 4; ++j)
        #pragma unroll
        for (int d = 0; d < DH; ++d) q[j][d] = sQh[j][head * DH + d];
    const float* Kb = khT + ((size_t)mesh * C + head * DH) * F;
    const float* Vb = vhT + ((size_t)mesh * C + head * DH) * F;
    float m[4], l[4], acc[4][DH];
    #pragma unroll
    for (int j = 0; j < 4; ++j) {
        m[j] = -1e30f; l[j] = 0.f;
        #pragma unroll
        for (int d = 0; d < DH; ++d) acc[j][d] = 0.f;
    }
    int st0 = sStart[0], st1 = sStart[1], st2 = sStart[2], st3 = sStart[3];
    for (int base = st0 & ~127; base < F; base += 128) {
        int p4 = base + 4 * sub;
        float sc[4][4];
        #pragma unroll
        for (int j = 0; j < 4; ++j)
            #pragma unroll
            for (int c = 0; c < 4; ++c) sc[j][c] = 0.f;
        #pragma unroll
        for (int d = 0; d < DH; ++d) {
            float4 kk = *(const float4*)(Kb + d * F + p4);
            #pragma unroll
            for (int j = 0; j < 4; ++j) {
                float a = q[j][d];
                sc[j][0] = fmaf(a, kk.x, sc[j][0]); sc[j][1] = fmaf(a, kk.y, sc[j][1]);
                sc[j][2] = fmaf(a, kk.z, sc[j][2]); sc[j][3] = fmaf(a, kk.w, sc[j][3]);
            }
        }
        #pragma unroll
        for (int c = 0; c < 4; ++c) {
            int pos = p4 + c;
            if (pos < st0) sc[0][c] = -1e30f;
            if (pos < st1) sc[1][c] = -1e30f;
            if (pos < st2) sc[2][c] = -1e30f;
            if (pos < st3) sc[3][c] = -1e30f;
        }
        float cj[4], px[4][4];
        #pragma unroll
        for (int j = 0; j < 4; ++j) {
            float mx = fmaxf(fmaxf(sc[j][0], sc[j][1]), fmaxf(sc[j][2], sc[j][3]));
            float mn = fmaxf(m[j], mx);
            cj[j] = __expf(m[j] - mn);
            px[j][0] = __expf(sc[j][0] - mn); px[j][1] = __expf(sc[j][1] - mn);
            px[j][2] = __expf(sc[j][2] - mn); px[j][3] = __expf(sc[j][3] - mn);
            l[j] = fmaf(l[j], cj[j], px[j][0] + px[j][1] + px[j][2] + px[j][3]);
            m[j] = mn;
        }
        #pragma unroll
        for (int d = 0; d < DH; ++d) {
            float4 vv = *(const float4*)(Vb + d * F + p4);
            #pragma unroll
            for (int j = 0; j < 4; ++j) {
                float w = fmaf(px[j][0], vv.x, fmaf(px[j][1], vv.y, fmaf(px[j][2], vv.z, px[j][3] * vv.w)));
                acc[j][d] = fmaf(acc[j][d], cj[j], w);
            }
        }
    }
    #pragma unroll
    for (int w = 16; w >= 1; w >>= 1) {
        #pragma unroll
        for (int j = 0; j < 4; ++j) {
            float mo = __shfl_xor(m[j], w), lo = __shfl_xor(l[j], w);
            float mn = fmaxf(m[j], mo);
            float ca = __expf(m[j] - mn), cb = __expf(mo - mn);
            l[j] = l[j] * ca + lo * cb;
            #pragma unroll
            for (int d = 0; d < DH; ++d) {
                float ao = __shfl_xor(acc[j][d], w);
                acc[j][d] = acc[j][d] * ca + ao * cb;
            }
            m[j] = mn;
        }
    }
    if (sub == 0) {
        #pragma unroll
        for (int j = 0; j < 4; ++j) {
            size_t sb = ((size_t)mesh * F + p0 + j) * H + head;
            sufM[sb] = m[j];
            sufL[sb] = l[j];
            #pragma unroll
            for (int d = 0; d < DH; ++d) sufA[sb * 16 + d] = acc[j][d];
        }
    }
}

// ---------------------------------------------------------------- K3b: persistent push-flood
// Per-(query,head) online-softmax state in registers (4 lanes/state, ring split 4-way).
// Cross-block data = ring-j new K/V only, via agent-scope atomic (write-through/IF-coherent)
// stores+loads -> NO threadfence/L2-writeback anywhere. Barrier = relaxed agent counter.
// 144 blocks x 1024 thr, ~98 KB LDS -> 1 block/CU, all co-resident.
#define DOT16(res, qv, a0, a1, a2, a3)                                        \
    res = qv[0] * a0.x;                res = fmaf(qv[1], a0.y, res);          \
    res = fmaf(qv[2], a0.z, res);      res = fmaf(qv[3], a0.w, res);          \
    res = fmaf(qv[4], a1.x, res);      res = fmaf(qv[5], a1.y, res);          \
    res = fmaf(qv[6], a1.z, res);      res = fmaf(qv[7], a1.w, res);          \
    res = fmaf(qv[8], a2.x, res);      res = fmaf(qv[9], a2.y, res);          \
    res = fmaf(qv[10], a2.z, res);     res = fmaf(qv[11], a2.w, res);         \
    res = fmaf(qv[12], a3.x, res);     res = fmaf(qv[13], a3.y, res);         \
    res = fmaf(qv[14], a3.z, res);     res = fmaf(qv[15], a3.w, res);

__global__ __launch_bounds__(NFT) void k_flood2(
        const int* __restrict__ ringStart, const int* __restrict__ invPerm,
        const float* __restrict__ qh_all, float* __restrict__ cur,
        float* __restrict__ kvK, float* __restrict__ kvV,
        const float* __restrict__ sufM, const float* __restrict__ sufL,
        const float* __restrict__ sufA,
        const float* __restrict__ Wk, const float* __restrict__ Wv, const float* __restrict__ Wo,
        int* gcount) {
    __shared__ __align__(16) float sK[MAXRING * C];   // aliased as merge buffer in finalize
    __shared__ __align__(16) float sV[MAXRING * C];
    __shared__ __align__(16) float sP[2][C];
    __shared__ __align__(16) float sNew[2][C];

    int bx = blockIdx.x, tid = threadIdx.x;
    int mesh = bx & 1, bi = bx >> 1;                  // bi in [0,72)
    int quarter = tid >> 8, r = tid & 255, h = r >> 5, qi = r & 31;
    int pos = qi * NFBM + bi;                         // owned sorted position
    int face = invPerm[pos];
    size_t qrow = ((size_t)mesh * F + face) * C + (h << 4);
    float qv[16];
    #pragma unroll
    for (int d = 0; d < 16; ++d) qv[d] = qh_all[qrow + d];
    float sm = -1e30f, sl = 0.f;
    float sacc[16];
    #pragma unroll
    for (int d = 0; d < 16; ++d) sacc[d] = 0.f;

    for (int lv = 0; lv < NLV; ++lv) {
        int rs = ringStart[lv], re = ringStart[lv + 1], ring = re - rs;
        __syncthreads();                              // sK(alias merge buf) reuse guard

        // ---------- finalize owned queries in [rs, re)  (block-uniform nf)
        bool fin = (pos >= rs) && (pos < re);
        int qi_min = (rs > bi) ? (rs - bi + NFBM - 1) / NFBM : 0;
        int qi_max = (re - 1 >= bi) ? (re - 1 - bi) / NFBM : -1;
        int nf = qi_max - qi_min + 1;
        if (nf > 0) {
            float* mrg = sK;                          // [slot2][h8][qi32][18]
            if (fin && (quarter & 1)) {
                float* p = &mrg[((((quarter >> 1) * 8 + h) * NQI) + qi) * 18];
                p[0] = sm; p[1] = sl;
                #pragma unroll
                for (int d = 0; d < 16; ++d) p[2 + d] = sacc[d];
            }
            __syncthreads();
            if (fin && !(quarter & 1)) {
                const float* p = &mrg[((((quarter >> 1) * 8 + h) * NQI) + qi) * 18];
                float mo = p[0], lo = p[1];
                float mn = fmaxf(sm, mo);
                float ca = __expf(sm - mn), cb = __expf(mo - mn);
                sl = sl * ca + lo * cb;
                #pragma unroll
                for (int d = 0; d < 16; ++d) sacc[d] = sacc[d] * ca + p[2 + d] * cb;
                sm = mn;
            }
            __syncthreads();
            if (fin && quarter == 2) {
                float* p = &mrg[((0 * 8 + h) * NQI + qi) * 18];
                p[0] = sm; p[1] = sl;
                #pragma unroll
                for (int d = 0; d < 16; ++d) p[2 + d] = sacc[d];
            }
            __syncthreads();
            if (fin && quarter == 0) {
                const float* p = &mrg[((0 * 8 + h) * NQI + qi) * 18];
                float mo = p[0], lo = p[1];
                float mn = fmaxf(sm, mo);
                float ca = __expf(sm - mn), cb = __expf(mo - mn);
                sl = sl * ca + lo * cb;
                #pragma unroll
                for (int d = 0; d < 16; ++d) sacc[d] = sacc[d] * ca + p[2 + d] * cb;
                sm = mn;
                // suffix partial (initial K/V over [startOfPos, F))
                size_t sb = ((size_t)mesh * F + pos) * H + h;
                float ms = sufM[sb], ls = sufL[sb];
                mn = fmaxf(sm, ms);
                ca = __expf(sm - mn); cb = __expf(ms - mn);
                sl = sl * ca + ls * cb;
                #pragma unroll
                for (int d = 0; d < 16; ++d) sacc[d] = sacc[d] * ca + sufA[sb * 16 + d] * cb;
                float inv = 1.f / sl;
                int slot = qi - qi_min;
                #pragma unroll
                for (int d = 0; d < 16; ++d) sP[slot][(h << 4) + d] = sacc[d] * inv;
            }
            __syncthreads();
            // Wo projection + residual
            for (int it = tid; it < nf * C; it += NFT) {
                int qq = it >> 7, ch = it & 127;
                int fpos = (qi_min + qq) * NFBM + bi;
                int fface = invPerm[fpos];
                const float* pr = sP[qq];
                float o = 0.f;
                for (int k = 0; k < C; k += 4) {
                    float4 pv = *(const float4*)&pr[k];
                    o = fmaf(pv.x, Wo[(k + 0) * C + ch], o);
                    o = fmaf(pv.y, Wo[(k + 1) * C + ch], o);
                    o = fmaf(pv.z, Wo[(k + 2) * C + ch], o);
                    o = fmaf(pv.w, Wo[(k + 3) * C + ch], o);
                }
                size_t rw = ((size_t)mesh * F + fface) * C + ch;
                float nv = cur[rw] + o;
                cur[rw] = nv;
                sNew[qq][ch] = nv;
            }
            __syncthreads();
            // Wk/Wv projection -> write-through new K/V (pos-major)
            for (int it = tid; it < nf * 2 * C; it += NFT) {
                int qq = it >> 8, cc = it & 255, ch = cc & 127;
                const float* W = (cc < C) ? Wk : Wv;
                const float* nr = sNew[qq];
                float a = 0.f;
                for (int k = 0; k < C; k += 4) {
                    float4 pv = *(const float4*)&nr[k];
                    a = fmaf(pv.x, W[(k + 0) * C + ch], a);
                    a = fmaf(pv.y, W[(k + 1) * C + ch], a);
                    a = fmaf(pv.z, W[(k + 2) * C + ch], a);
                    a = fmaf(pv.w, W[(k + 3) * C + ch], a);
                }
                int fpos = (qi_min + qq) * NFBM + bi;
                float* dst = ((cc < C) ? kvK : kvV) + ((size_t)mesh * F + fpos) * C + ch;
                __hip_atomic_store(dst, a, __ATOMIC_RELAXED, __HIP_MEMORY_SCOPE_AGENT);
            }
        }

        // ---------- grid barrier (fence-free: comms are agent-scope write-through)
        __syncthreads();                              // all waves drain vmcnt before arrive
        if (tid == 0) {
            asm volatile("s_waitcnt vmcnt(0)" ::: "memory");
            __hip_atomic_fetch_add(gcount, 1, __ATOMIC_RELAXED, __HIP_MEMORY_SCOPE_AGENT);
            int target = NFB * (lv + 1);
            while (__hip_atomic_load(gcount, __ATOMIC_RELAXED, __HIP_MEMORY_SCOPE_AGENT) < target)
                __builtin_amdgcn_s_sleep(2);
        }
        __syncthreads();

        // ---------- stage ring-j K/V, accumulate into pending states
        int maxPos = (NQI - 1) * NFBM + bi;
        if (maxPos >= re) {                           // block-uniform
            for (int i = tid; i < ring * C; i += NFT) {
                int kk = i >> 7, ch = i & 127;
                size_t src = ((size_t)mesh * F + rs + kk) * C + ch;
                sK[kk * C + ch] = __hip_atomic_load(&kvK[src], __ATOMIC_RELAXED, __HIP_MEMORY_SCOPE_AGENT);
                sV[kk * C + ch] = __hip_atomic_load(&kvV[src], __ATOMIC_RELAXED, __HIP_MEMORY_SCOPE_AGENT);
            }
            __syncthreads();
            if (pos >= re) {                          // pending lanes only
                int k0 = (quarter * ring) >> 2, k1 = ((quarter + 1) * ring) >> 2;
                for (int k = k0; k < k1; ++k) {
                    const float4* kp = (const float4*)&sK[k * C + (h << 4)];
                    float4 a0 = kp[0], a1 = kp[1], a2 = kp[2], a3 = kp[3];
                    float s;
                    DOT16(s, qv, a0, a1, a2, a3)
                    float mn = fmaxf(sm, s);
                    float c = __expf(sm - mn), p = __expf(s - mn);
                    sl = sl * c + p;
                    sm = mn;
                    const float4* vp = (const float4*)&sV[k * C + (h << 4)];
                    float4 b0 = vp[0], b1 = vp[1], b2 = vp[2], b3 = vp[3];
                    sacc[0]  = sacc[0]  * c + p * b0.x;  sacc[1]  = sacc[1]  * c + p * b0.y;
                    sacc[2]  = sacc[2]  * c + p * b0.z;  sacc[3]  = sacc[3]  * c + p * b0.w;
                    sacc[4]  = sacc[4]  * c + p * b1.x;  sacc[5]  = sacc[5]  * c + p * b1.y;
                    sacc[6]  = sacc[6]  * c + p * b1.z;  sacc[7]  = sacc[7]  * c + p * b1.w;
                    sacc[8]  = sacc[8]  * c + p * b2.x;  sacc[9]  = sacc[9]  * c + p * b2.y;
                    sacc[10] = sacc[10] * c + p * b2.z;  sacc[11] = sacc[11] * c + p * b2.w;
                    sacc[12] = sacc[12] * c + p * b3.x;  sacc[13] = sacc[13] * c + p * b3.y;
                    sacc[14] = sacc[14] * c + p * b3.z;  sacc[15] = sacc[15] * c + p * b3.w;
                }
            }
        }
    }
}

// ---------------------------------------------------------------- K4: MLP + sigmoid (b128 LDS reads)
__global__ __launch_bounds__(256) void k_mlp(
        const float* __restrict__ cur,
        const float* __restrict__ W1, const float* __restrict__ b1,
        const float* __restrict__ W2, const float* __restrict__ b2,
        const float* __restrict__ W3, const float* __restrict__ b3,
        const float* __restrict__ W4, const float* __restrict__ b4,
        const float* __restrict__ W5, const float* __restrict__ b5,
        float* __restrict__ out_scores) {
    __shared__ __align__(16) float sIn[8][C];
    __shared__ __align__(16) float sA[8][WID];
    __shared__ __align__(16) float sB[8][WID];
    int tid = threadIdx.x;
    int r0 = blockIdx.x * 8;
    for (int i = tid; i < 8 * C; i += 256) sIn[i >> 7][i & 127] = cur[(size_t)r0 * C + i];
    __syncthreads();
    {
        float a[8];
        #pragma unroll
        for (int r = 0; r < 8; ++r) a[r] = 0.f;
        for (int k = 0; k < C; k += 4) {
            float w0 = W1[(k + 0) * WID + tid], w1 = W1[(k + 1) * WID + tid];
            float w2 = W1[(k + 2) * WID + tid], w3 = W1[(k + 3) * WID + tid];
            #pragma unroll
            for (int r = 0; r < 8; ++r) {
                float4 xv = *(const float4*)&sIn[r][k];
                a[r] = fmaf(xv.x, w0, fmaf(xv.y, w1, fmaf(xv.z, w2, fmaf(xv.w, w3, a[r]))));
            }
        }
        float bias = b1[tid];
        #pragma unroll
        for (int r = 0; r < 8; ++r) sA[r][tid] = fmaxf(a[r] + bias, 0.f);
    }
    __syncthreads();
    {
        float a[8];
        #pragma unroll
        for (int r = 0; r < 8; ++r) a[r] = 0.f;
        for (int k = 0; k < WID; k += 4) {
            float w0 = W2[(k + 0) * WID + tid], w1 = W2[(k + 1) * WID + tid];
            float w2 = W2[(k + 2) * WID + tid], w3 = W2[(k + 3) * WID + tid];
            #pragma unroll
            for (int r = 0; r < 8; ++r) {
                float4 xv = *(const float4*)&sA[r][k];
                a[r] = fmaf(xv.x, w0, fmaf(xv.y, w1, fmaf(xv.z, w2, fmaf(xv.w, w3, a[r]))));
            }
        }
        float bias = b2[tid];
        #pragma unroll
        for (int r = 0; r < 8; ++r) sB[r][tid] = fmaxf(a[r] + bias, 0.f);
    }
    __syncthreads();
    {
        float a[8];
        #pragma unroll
        for (int r = 0; r < 8; ++r) a[r] = 0.f;
        for (int k = 0; k < WID; k += 4) {
            float w0 = W3[(k + 0) * WID + tid], w1 = W3[(k + 1) * WID + tid];
            float w2 = W3[(k + 2) * WID + tid], w3 = W3[(k + 3) * WID + tid];
            #pragma unroll
            for (int r = 0; r < 8; ++r) {
                float4 xv = *(const float4*)&sB[r][k];
                a[r] = fmaf(xv.x, w0, fmaf(xv.y, w1, fmaf(xv.z, w2, fmaf(xv.w, w3, a[r]))));
            }
        }
        float bias = b3[tid];
        #pragma unroll
        for (int r = 0; r < 8; ++r) sA[r][tid] = fmaxf(a[r] + bias, 0.f);
    }
    __syncthreads();
    {
        float a[8];
        #pragma unroll
        for (int r = 0; r < 8; ++r) a[r] = 0.f;
        for (int k = 0; k < WID; k += 4) {
            float w0 = W4[(k + 0) * WID + tid], w1 = W4[(k + 1) * WID + tid];
            float w2 = W4[(k + 2) * WID + tid], w3 = W4[(k + 3) * WID + tid];
            #pragma unroll
            for (int r = 0; r < 8; ++r) {
                float4 xv = *(const float4*)&sA[r][k];
                a[r] = fmaf(xv.x, w0, fmaf(xv.y, w1, fmaf(xv.z, w2, fmaf(xv.w, w3, a[r]))));
            }
        }
        float bias = b4[tid];
        #pragma unroll
        for (int r = 0; r < 8; ++r) sB[r][tid] = fmaxf(a[r] + bias, 0.f);
    }
    __syncthreads();
    if (tid < 8) {
        float a = b5[0];
        for (int k = 0; k < WID; ++k) a = fmaf(sB[tid][k], W5[k], a);
        out_scores[r0 + tid] = 1.f / (1.f + __expf(-a));
    }
}

// ---------------------------------------------------------------- K5: cur[B,F,C] -> out0[B,C,F]
__global__ void k_transpose_out(const float* __restrict__ cur, float* __restrict__ out) {
    __shared__ float tile[32][33];
    int b = blockIdx.z;
    int f0 = blockIdx.x * 32, c0 = blockIdx.y * 32;
    int tx = threadIdx.x, ty = threadIdx.y;
    #pragma unroll
    for (int i = 0; i < 4; ++i) {
        int f = f0 + ty + i * 8;
        tile[ty + i * 8][tx] = cur[((size_t)b * F + f) * C + c0 + tx];
    }
    __syncthreads();
    #pragma unroll
    for (int i = 0; i < 4; ++i) {
        int c = c0 + ty + i * 8;
        out[((size_t)b * C + c) * F + f0 + tx] = tile[tx][ty + i * 8];
    }
}

// ----------------------------------------------------------------
extern "C" void kernel_launch(void* const* d_in, const int* in_sizes, int n_in,
                              void* d_out, int out_size, void* d_ws, size_t ws_size,
                              hipStream_t stream) {
    const size_t n = (size_t)NB * F * C;          // 589824
    float* cur  = (float*)d_ws;
    float* qh   = cur + n;
    float* khT  = qh + n;                         // ch-major (k_suffix input)
    float* vhT  = khT + n;
    float* kvK  = vhT + n;                        // pos-major (flood comms, final-only)
    float* kvV  = kvK + n;
    float* sufM = kvV + n;                        // [NB][F][H]
    float* sufL = sufM + (size_t)NB * F * H;
    float* sufA = sufL + (size_t)NB * F * H;      // [NB][F][H][16]
    float* wbuf = sufA + (size_t)NB * F * H * 16;
    int*   permIdx    = (int*)(wbuf + 296193 + 3);
    int*   invPerm    = permIdx + F;
    int*   startOfPos = invPerm + F;
    int*   ringStartD = startOfPos + F;
    int*   flag       = ringStartD + NLV + 1;
    int*   gcount     = flag + 1;

    const int oWq = 0,       oWk = 16384,  oWv = 32768,  oWo = 49152;
    const int oW1 = 65536,   oB1 = 98304;
    const int oW2 = 98560,   oB2 = 164096;
    const int oW3 = 164352,  oB3 = 229888;
    const int oW4 = 230144,  oB4 = 295680;
    const int oW5 = 295936,  oB5 = 296192;
    const int wtot = 296193;

    WSegs segs = {{
        { d_in[1],  oWq, 16384 }, { d_in[2],  oWk, 16384 },
        { d_in[3],  oWv, 16384 }, { d_in[4],  oWo, 16384 },
        { d_in[5],  oW1, 32768 }, { d_in[6],  oB1, 256 },
        { d_in[7],  oW2, 65536 }, { d_in[8],  oB2, 256 },
        { d_in[9],  oW3, 65536 }, { d_in[10], oB3, 256 },
        { d_in[11], oW4, 65536 }, { d_in[12], oB4, 256 },
        { d_in[13], oW5, 256 },   { d_in[14], oB5, 1 },
    }};

    float* out0 = (float*)d_out;                  // [B,C,F] fp32
    float* out1 = out0 + (size_t)NB * C * F;      // [B,F,1] fp32

    k_detect<<<1, 256, 0, stream>>>(d_in[0], flag);
    k_perm<<<1, 256, 0, stream>>>(permIdx, invPerm, startOfPos, ringStartD, gcount);
    k_convert<<<(wtot + 255) / 256, 256, 0, stream>>>(segs, flag, wbuf, wtot);
    k_transpose_in<<<dim3(F / 32, C / 32, NB), dim3(32, 8), 0, stream>>>(d_in[0], flag, cur);
    k_proj_init<<<(NB * F) / 8, 128, 0, stream>>>(cur, permIdx, wbuf + oWq, wbuf + oWk, wbuf + oWv,
                                                  qh, khT, vhT);
    k_suffix<<<NB * (F / 4), 256, 0, stream>>>(invPerm, startOfPos, qh, khT, vhT, sufM, sufL, sufA);
    k_flood2<<<NFB, NFT, 0, stream>>>(ringStartD, invPerm, qh, cur, kvK, kvV,
                                      sufM, sufL, sufA,
                                      wbuf + oWk, wbuf + oWv, wbuf + oWo, gcount);
    k_mlp<<<(NB * F) / 8, 256, 0, stream>>>(cur, wbuf + oW1, wbuf + oB1, wbuf + oW2, wbuf + oB2,
                                            wbuf + oW3, wbuf + oB3, wbuf + oW4, wbuf + oB4,
                                            wbuf + oW5, wbuf + oB5, out1);
    k_transpose_out<<<dim3(F / 32, C / 32, NB), dim3(32, 8), 0, stream>>>(cur, out0);
}

// Round 7
// 2453.612 us; speedup vs baseline: 1.7197x; 1.7197x over previous
//
#include <hip/hip_runtime.h>
#include <hip/hip_bf16.h>
#include <stdint.h>

#define GRIDN 48
#define F 2304
#define C 128
#define H 8
#define DH 16
#define NB 2          // batch (meshes)
#define WID 256
#define NLV 49        // BFS levels for GRID=48, anchor at (24,24)

typedef __hip_bfloat16 bf16;
typedef unsigned short ushort_t;

__device__ __forceinline__ float b2f(bf16 v) { return __bfloat162float(v); }

__device__ __forceinline__ ushort_t f2bu(float f) {
    __hip_bfloat16 b = __float2bfloat16(f);
    return *(ushort_t*)&b;
}

// unpack 4 bf16 (memory order) from uint2
__device__ __forceinline__ void unp4(uint2 u, float& a, float& b, float& c, float& d) {
    a = __uint_as_float(u.x << 16);
    b = __uint_as_float(u.x & 0xffff0000u);
    c = __uint_as_float(u.y << 16);
    d = __uint_as_float(u.y & 0xffff0000u);
}

// ---------------------------------------------------------------- K-1: input dtype detector
__global__ void k_detect(const void* __restrict__ x, int* __restrict__ flag) {
    __shared__ int bad;
    if (threadIdx.x == 0) bad = 0;
    __syncthreads();
    const bf16* xb = (const bf16*)x;
    int insane = 0;
    #pragma unroll
    for (int i = 0; i < 8; ++i) {
        float v = b2f(xb[threadIdx.x * 8 + i]);
        if (!(fabsf(v) < 1e10f)) insane = 1;
    }
    if (insane) atomicOr(&bad, 1);
    __syncthreads();
    if (threadIdx.x == 0) *flag = bad;
}

// ---------------------------------------------------------------- K0: ring permutation tables
__global__ void k_perm(int* __restrict__ permIdx, int* __restrict__ invPerm,
                       int* __restrict__ startOfPos, int* __restrict__ ringStart) {
    __shared__ int cnt[NLV], start[NLV], rs0[NLV];
    int t = threadIdx.x;
    if (t < NLV) cnt[t] = 0;
    __syncthreads();
    for (int f = t; f < F; f += 256) {
        int d = abs(f / GRIDN - GRIDN / 2) + abs(f % GRIDN - GRIDN / 2);
        atomicAdd(&cnt[d], 1);
    }
    __syncthreads();
    if (t == 0) {
        int s = 0;
        for (int l = 0; l < NLV; ++l) { start[l] = s; rs0[l] = s; ringStart[l] = s; s += cnt[l]; }
        ringStart[NLV] = s;
    }
    __syncthreads();
    for (int f = t; f < F; f += 256) {
        int d = abs(f / GRIDN - GRIDN / 2) + abs(f % GRIDN - GRIDN / 2);
        int p = atomicAdd(&start[d], 1);
        permIdx[f] = p;
        invPerm[p] = f;
        startOfPos[p] = rs0[d];
    }
}

// ---------------------------------------------------------------- K0b: weights -> fp32
struct WSeg { const void* src; int off; int cnt; };
struct WSegs { WSeg s[14]; };

__global__ void k_convert(WSegs segs, const int* __restrict__ flag,
                          float* __restrict__ dst, int total) {
    int i = blockIdx.x * blockDim.x + threadIdx.x;
    if (i >= total) return;
    bool f32 = (*flag != 0);
    #pragma unroll 1
    for (int j = 0; j < 14; ++j) {
        int off = segs.s[j].off, cnt = segs.s[j].cnt;
        if (i >= off && i < off + cnt) {
            int k = i - off;
            dst[i] = f32 ? ((const float*)segs.s[j].src)[k]
                         : b2f(((const bf16*)segs.s[j].src)[k]);
            return;
        }
    }
}

// ---------------------------------------------------------------- K1: x[B,C,F] -> cur[B,F,C]
__global__ void k_transpose_in(const void* __restrict__ x, const int* __restrict__ flag,
                               float* __restrict__ cur) {
    __shared__ float tile[32][33];
    bool f32 = (*flag != 0);
    int b = blockIdx.z;
    int f0 = blockIdx.x * 32, c0 = blockIdx.y * 32;
    int tx = threadIdx.x, ty = threadIdx.y;
    #pragma unroll
    for (int i = 0; i < 4; ++i) {
        int c = c0 + ty + i * 8;
        size_t idx = ((size_t)b * C + c) * F + f0 + tx;
        tile[ty + i * 8][tx] = f32 ? ((const float*)x)[idx] : b2f(((const bf16*)x)[idx]);
    }
    __syncthreads();
    #pragma unroll
    for (int i = 0; i < 4; ++i) {
        int f = f0 + ty + i * 8;
        cur[((size_t)b * F + f) * C + c0 + tx] = tile[tx][ty + i * 8];
    }
}

// ---------------------------------------------------------------- K2: projections; khT/vhT bf16 [mesh][ch][pos]
__global__ __launch_bounds__(128) void k_proj_init(
        const float* __restrict__ cur, const int* __restrict__ permIdx,
        const float* __restrict__ Wq, const float* __restrict__ Wk, const float* __restrict__ Wv,
        float* __restrict__ qh, ushort_t* __restrict__ khT, ushort_t* __restrict__ vhT) {
    __shared__ float rows[8][C];
    int r0 = blockIdx.x * 8;
    int tid = threadIdx.x;
    #pragma unroll
    for (int r = 0; r < 8; ++r) rows[r][tid] = cur[(size_t)(r0 + r) * C + tid];
    __syncthreads();
    float aq[8], ak[8], av[8];
    #pragma unroll
    for (int r = 0; r < 8; ++r) { aq[r] = 0.f; ak[r] = 0.f; av[r] = 0.f; }
    for (int k = 0; k < C; ++k) {
        float wq = Wq[k * C + tid];
        float wk = Wk[k * C + tid];
        float wv = Wv[k * C + tid];
        #pragma unroll
        for (int r = 0; r < 8; ++r) {
            float xv = rows[r][k];
            aq[r] = fmaf(xv, wq, aq[r]);
            ak[r] = fmaf(xv, wk, ak[r]);
            av[r] = fmaf(xv, wv, av[r]);
        }
    }
    const float scale = 0.25f;
    #pragma unroll
    for (int r = 0; r < 8; ++r) {
        int grow = r0 + r;
        int mesh = grow / F, face = grow % F;
        int p = permIdx[face];
        qh[(size_t)grow * C + tid] = aq[r] * scale;
        khT[((size_t)mesh * C + tid) * F + p] = f2bu(ak[r]);
        vhT[((size_t)mesh * C + tid) * F + p] = f2bu(av[r]);
    }
}

// ---------------------------------------------------------------- K3a: suffix attention (initial K/V, bf16), 4 q/block
__global__ __launch_bounds__(256) void k_suffix(
        const int* __restrict__ invPerm, const int* __restrict__ startOfPos,
        const float* __restrict__ qh_all,
        const ushort_t* __restrict__ khT, const ushort_t* __restrict__ vhT,
        float* __restrict__ sufM, float* __restrict__ sufL, float* __restrict__ sufA) {
    int bx = blockIdx.x;
    int mesh = bx & 1;
    int p0 = (bx >> 1) * 4;
    int tid = threadIdx.x;
    __shared__ float sQh[4][C];
    __shared__ int sFace[4], sStart[4];
    if (tid < 4) {
        sFace[tid] = invPerm[p0 + tid];
        sStart[tid] = startOfPos[p0 + tid];
    }
    __syncthreads();
    {
        int j = tid >> 7, ch = tid & 127;
        sQh[j][ch]     = qh_all[((size_t)mesh * F + sFace[j]) * C + ch];
        sQh[j + 2][ch] = qh_all[((size_t)mesh * F + sFace[j + 2]) * C + ch];
    }
    __syncthreads();
    int head = tid >> 5, sub = tid & 31;
    float q[4][DH];
    #pragma unroll
    for (int j = 0; j < 4; ++j)
        #pragma unroll
        for (int d = 0; d < DH; ++d) q[j][d] = sQh[j][head * DH + d];
    const ushort_t* Kb = khT + ((size_t)mesh * C + head * DH) * F;
    const ushort_t* Vb = vhT + ((size_t)mesh * C + head * DH) * F;
    float m[4], l[4], acc[4][DH];
    #pragma unroll
    for (int j = 0; j < 4; ++j) {
        m[j] = -1e30f; l[j] = 0.f;
        #pragma unroll
        for (int d = 0; d < DH; ++d) acc[j][d] = 0.f;
    }
    int st0 = sStart[0], st1 = sStart[1], st2 = sStart[2], st3 = sStart[3];
    for (int base = st0 & ~127; base < F; base += 128) {
        int p4 = base + 4 * sub;
        float sc[4][4];
        #pragma unroll
        for (int j = 0; j < 4; ++j)
            #pragma unroll
            for (int c = 0; c < 4; ++c) sc[j][c] = 0.f;
        #pragma unroll
        for (int d = 0; d < DH; ++d) {
            uint2 u = *(const uint2*)(Kb + (size_t)d * F + p4);
            float kx, ky, kz, kw;
            unp4(u, kx, ky, kz, kw);
            #pragma unroll
            for (int j = 0; j < 4; ++j) {
                float a = q[j][d];
                sc[j][0] = fmaf(a, kx, sc[j][0]); sc[j][1] = fmaf(a, ky, sc[j][1]);
                sc[j][2] = fmaf(a, kz, sc[j][2]); sc[j][3] = fmaf(a, kw, sc[j][3]);
            }
        }
        #pragma unroll
        for (int c = 0; c < 4; ++c) {
            int pos = p4 + c;
            if (pos < st0) sc[0][c] = -1e30f;
            if (pos < st1) sc[1][c] = -1e30f;
            if (pos < st2) sc[2][c] = -1e30f;
            if (pos < st3) sc[3][c] = -1e30f;
        }
        float cj[4], px[4][4];
        #pragma unroll
        for (int j = 0; j < 4; ++j) {
            float mx = fmaxf(fmaxf(sc[j][0], sc[j][1]), fmaxf(sc[j][2], sc[j][3]));
            float mn = fmaxf(m[j], mx);
            cj[j] = __expf(m[j] - mn);
            px[j][0] = __expf(sc[j][0] - mn); px[j][1] = __expf(sc[j][1] - mn);
            px[j][2] = __expf(sc[j][2] - mn); px[j][3] = __expf(sc[j][3] - mn);
            l[j] = fmaf(l[j], cj[j], px[j][0] + px[j][1] + px[j][2] + px[j][3]);
            m[j] = mn;
        }
        #pragma unroll
        for (int d = 0; d < DH; ++d) {
            uint2 u = *(const uint2*)(Vb + (size_t)d * F + p4);
            float vx, vy, vz, vw;
            unp4(u, vx, vy, vz, vw);
            #pragma unroll
            for (int j = 0; j < 4; ++j) {
                float w = fmaf(px[j][0], vx, fmaf(px[j][1], vy, fmaf(px[j][2], vz, px[j][3] * vw)));
                acc[j][d] = fmaf(acc[j][d], cj[j], w);
            }
        }
    }
    #pragma unroll
    for (int w = 16; w >= 1; w >>= 1) {
        #pragma unroll
        for (int j = 0; j < 4; ++j) {
            float mo = __shfl_xor(m[j], w), lo = __shfl_xor(l[j], w);
            float mn = fmaxf(m[j], mo);
            float ca = __expf(m[j] - mn), cb = __expf(mo - mn);
            l[j] = l[j] * ca + lo * cb;
            #pragma unroll
            for (int d = 0; d < DH; ++d) {
                float ao = __shfl_xor(acc[j][d], w);
                acc[j][d] = acc[j][d] * ca + ao * cb;
            }
            m[j] = mn;
        }
    }
    if (sub == 0) {
        #pragma unroll
        for (int j = 0; j < 4; ++j) {
            size_t sb = ((size_t)mesh * F + p0 + j) * H + head;
            sufM[sb] = m[j];
            sufL[sb] = l[j];
            #pragma unroll
            for (int d = 0; d < DH; ++d) sufA[sb * 16 + d] = acc[j][d];
        }
    }
}

// ---------------------------------------------------------------- K3b: one BFS level, prefix-only, 4 q/block
// 512 threads = 4 q x 8 h x 16 lanes. Prefix keys [0, rs) scanned from bf16
// khT/vhT; merged with precomputed suffix partial; epilogue updates cur and
// the block's own K/V columns (disjoint from prefix -> no race).
__global__ __launch_bounds__(512) void k_level(
        int rs, int re,
        const int* __restrict__ invPerm,
        const float* __restrict__ qh_all, float* __restrict__ cur,
        ushort_t* __restrict__ khT, ushort_t* __restrict__ vhT,
        const float* __restrict__ sufM, const float* __restrict__ sufL,
        const float* __restrict__ sufA,
        const float* __restrict__ Wk, const float* __restrict__ Wv, const float* __restrict__ Wo) {
    int bx = blockIdx.x;
    int mesh = bx & 1;
    int p0 = rs + (bx >> 1) * 4;
    int tid = threadIdx.x;
    int q = tid >> 7, h = (tid >> 4) & 7, ln = tid & 15;
    __shared__ int sFace[4];
    __shared__ float sP[4][C];
    __shared__ float sNew[4][C];
    if (tid < 4) {
        int pp = p0 + tid;
        sFace[tid] = invPerm[pp < re ? pp : re - 1];
    }
    __syncthreads();
    int p = p0 + q;
    int pc = p < re ? p : re - 1;
    int face = sFace[q];
    size_t qrow = ((size_t)mesh * F + face) * C + h * DH;
    float qv[DH];
    #pragma unroll
    for (int d = 0; d < DH; ++d) qv[d] = qh_all[qrow + d];
    const ushort_t* Kb = khT + ((size_t)mesh * C + h * DH) * F;
    const ushort_t* Vb = vhT + ((size_t)mesh * C + h * DH) * F;

    float m = -1e30f, l = 0.f;
    float acc[DH];
    #pragma unroll
    for (int d = 0; d < DH; ++d) acc[d] = 0.f;

    for (int base = 0; base < rs; base += 64) {
        int p4 = base + 4 * ln;
        float sx = 0, sy = 0, sz = 0, sw = 0;
        #pragma unroll
        for (int d = 0; d < DH; ++d) {
            uint2 u = *(const uint2*)(Kb + (size_t)d * F + p4);
            float kx, ky, kz, kw;
            unp4(u, kx, ky, kz, kw);
            float a = qv[d];
            sx = fmaf(a, kx, sx); sy = fmaf(a, ky, sy);
            sz = fmaf(a, kz, sz); sw = fmaf(a, kw, sw);
        }
        if (base + 64 > rs) {                 // tail: mask keys at pos >= rs
            if (p4 + 0 >= rs) sx = -1e30f;
            if (p4 + 1 >= rs) sy = -1e30f;
            if (p4 + 2 >= rs) sz = -1e30f;
            if (p4 + 3 >= rs) sw = -1e30f;
        }
        float mx = fmaxf(fmaxf(sx, sy), fmaxf(sz, sw));
        float mn = fmaxf(m, mx);
        float c = __expf(m - mn);
        float px = __expf(sx - mn), py = __expf(sy - mn);
        float pz = __expf(sz - mn), pw = __expf(sw - mn);
        l = fmaf(l, c, px + py + pz + pw);
        m = mn;
        #pragma unroll
        for (int d = 0; d < DH; ++d) {
            uint2 u = *(const uint2*)(Vb + (size_t)d * F + p4);
            float vx, vy, vz, vw;
            unp4(u, vx, vy, vz, vw);
            float w = fmaf(px, vx, fmaf(py, vy, fmaf(pz, vz, pw * vw)));
            acc[d] = fmaf(acc[d], c, w);
        }
    }
    // merge 16 lanes of this (q,h) group
    #pragma unroll
    for (int w = 8; w >= 1; w >>= 1) {
        float mo = __shfl_xor(m, w), lo = __shfl_xor(l, w);
        float mn = fmaxf(m, mo);
        float ca = __expf(m - mn), cb = __expf(mo - mn);
        l = l * ca + lo * cb;
        #pragma unroll
        for (int d = 0; d < DH; ++d) {
            float ao = __shfl_xor(acc[d], w);
            acc[d] = acc[d] * ca + ao * cb;
        }
        m = mn;
    }
    if (ln == 0) {                            // merge with suffix partial, normalize
        size_t sb = ((size_t)mesh * F + pc) * H + h;
        float ms = sufM[sb], ls = sufL[sb];
        float mn = fmaxf(m, ms);
        float e1 = __expf(m - mn), e2 = __expf(ms - mn);
        float den = fmaf(l, e1, ls * e2);
        float inv = 1.f / den;
        #pragma unroll
        for (int d = 0; d < DH; ++d)
            sP[q][h * DH + d] = fmaf(acc[d], e1, sufA[sb * 16 + d] * e2) * inv;
    }
    __syncthreads();
    {   // Wo projection + residual: 512 thr = 4q x 128 ch
        int ch = tid & 127;
        const float* pr = sP[q];
        float o = 0.f;
        for (int k = 0; k < C; k += 4) {
            float4 pv = *(const float4*)&pr[k];
            o = fmaf(pv.x, Wo[(k + 0) * C + ch], o);
            o = fmaf(pv.y, Wo[(k + 1) * C + ch], o);
            o = fmaf(pv.z, Wo[(k + 2) * C + ch], o);
            o = fmaf(pv.w, Wo[(k + 3) * C + ch], o);
        }
        size_t rw = ((size_t)mesh * F + face) * C + ch;
        float nv = cur[rw] + o;
        sNew[q][ch] = nv;
        if (p < re) cur[rw] = nv;
    }
    __syncthreads();
    // K/V refresh at own ring columns (bf16 scatter)
    for (int it = tid; it < 4 * 2 * C; it += 512) {
        int qq = it >> 8, cc = it & 255, ch = cc & 127;
        int pq = p0 + qq;
        if (pq >= re) continue;
        const float* W = (cc < C) ? Wk : Wv;
        const float* nr = sNew[qq];
        float a = 0.f;
        for (int k = 0; k < C; k += 4) {
            float4 pv = *(const float4*)&nr[k];
            a = fmaf(pv.x, W[(k + 0) * C + ch], a);
            a = fmaf(pv.y, W[(k + 1) * C + ch], a);
            a = fmaf(pv.z, W[(k + 2) * C + ch], a);
            a = fmaf(pv.w, W[(k + 3) * C + ch], a);
        }
        ushort_t* dst = ((cc < C) ? khT : vhT) + ((size_t)mesh * C + ch) * F + pq;
        *dst = f2bu(a);
    }
}

// ---------------------------------------------------------------- K4: MLP + sigmoid, 4 rows/block (1152 blocks)
__global__ __launch_bounds__(256) void k_mlp(
        const float* __restrict__ cur,
        const float* __restrict__ W1, const float* __restrict__ b1,
        const float* __restrict__ W2, const float* __restrict__ b2,
        const float* __restrict__ W3, const float* __restrict__ b3,
        const float* __restrict__ W4, const float* __restrict__ b4,
        const float* __restrict__ W5, const float* __restrict__ b5,
        float* __restrict__ out_scores) {
    __shared__ __align__(16) float sIn[4][C];
    __shared__ __align__(16) float sA[4][WID];
    __shared__ __align__(16) float sB[4][WID];
    int tid = threadIdx.x;
    int r0 = blockIdx.x * 4;
    for (int i = tid; i < 4 * C; i += 256) sIn[i >> 7][i & 127] = cur[(size_t)r0 * C + i];
    __syncthreads();
    {
        float a[4];
        #pragma unroll
        for (int r = 0; r < 4; ++r) a[r] = 0.f;
        for (int k = 0; k < C; k += 4) {
            float w0 = W1[(k + 0) * WID + tid], w1 = W1[(k + 1) * WID + tid];
            float w2 = W1[(k + 2) * WID + tid], w3 = W1[(k + 3) * WID + tid];
            #pragma unroll
            for (int r = 0; r < 4; ++r) {
                float4 xv = *(const float4*)&sIn[r][k];
                a[r] = fmaf(xv.x, w0, fmaf(xv.y, w1, fmaf(xv.z, w2, fmaf(xv.w, w3, a[r]))));
            }
        }
        float bias = b1[tid];
        #pragma unroll
        for (int r = 0; r < 4; ++r) sA[r][tid] = fmaxf(a[r] + bias, 0.f);
    }
    __syncthreads();
    {
        float a[4];
        #pragma unroll
        for (int r = 0; r < 4; ++r) a[r] = 0.f;
        for (int k = 0; k < WID; k += 4) {
            float w0 = W2[(k + 0) * WID + tid], w1 = W2[(k + 1) * WID + tid];
            float w2 = W2[(k + 2) * WID + tid], w3 = W2[(k + 3) * WID + tid];
            #pragma unroll
            for (int r = 0; r < 4; ++r) {
                float4 xv = *(const float4*)&sA[r][k];
                a[r] = fmaf(xv.x, w0, fmaf(xv.y, w1, fmaf(xv.z, w2, fmaf(xv.w, w3, a[r]))));
            }
        }
        float bias = b2[tid];
        #pragma unroll
        for (int r = 0; r < 4; ++r) sB[r][tid] = fmaxf(a[r] + bias, 0.f);
    }
    __syncthreads();
    {
        float a[4];
        #pragma unroll
        for (int r = 0; r < 4; ++r) a[r] = 0.f;
        for (int k = 0; k < WID; k += 4) {
            float w0 = W3[(k + 0) * WID + tid], w1 = W3[(k + 1) * WID + tid];
            float w2 = W3[(k + 2) * WID + tid], w3 = W3[(k + 3) * WID + tid];
            #pragma unroll
            for (int r = 0; r < 4; ++r) {
                float4 xv = *(const float4*)&sB[r][k];
                a[r] = fmaf(xv.x, w0, fmaf(xv.y, w1, fmaf(xv.z, w2, fmaf(xv.w, w3, a[r]))));
            }
        }
        float bias = b3[tid];
        #pragma unroll
        for (int r = 0; r < 4; ++r) sA[r][tid] = fmaxf(a[r] + bias, 0.f);
    }
    __syncthreads();
    {
        float a[4];
        #pragma unroll
        for (int r = 0; r < 4; ++r) a[r] = 0.f;
        for (int k = 0; k < WID; k += 4) {
            float w0 = W4[(k + 0) * WID + tid], w1 = W4[(k + 1) * WID + tid];
            float w2 = W4[(k + 2) * WID + tid], w3 = W4[(k + 3) * WID + tid];
            #pragma unroll
            for (int r = 0; r < 4; ++r) {
                float4 xv = *(const float4*)&sA[r][k];
                a[r] = fmaf(xv.x, w0, fmaf(xv.y, w1, fmaf(xv.z, w2, fmaf(xv.w, w3, a[r]))));
            }
        }
        float bias = b4[tid];
        #pragma unroll
        for (int r = 0; r < 4; ++r) sB[r][tid] = fmaxf(a[r] + bias, 0.f);
    }
    __syncthreads();
    if (tid < 4) {
        float a = b5[0];
        for (int k = 0; k < WID; ++k) a = fmaf(sB[tid][k], W5[k], a);
        out_scores[r0 + tid] = 1.f / (1.f + __expf(-a));
    }
}

// ---------------------------------------------------------------- K5: cur[B,F,C] -> out0[B,C,F]
__global__ void k_transpose_out(const float* __restrict__ cur, float* __restrict__ out) {
    __shared__ float tile[32][33];
    int b = blockIdx.z;
    int f0 = blockIdx.x * 32, c0 = blockIdx.y * 32;
    int tx = threadIdx.x, ty = threadIdx.y;
    #pragma unroll
    for (int i = 0; i < 4; ++i) {
        int f = f0 + ty + i * 8;
        tile[ty + i * 8][tx] = cur[((size_t)b * F + f) * C + c0 + tx];
    }
    __syncthreads();
    #pragma unroll
    for (int i = 0; i < 4; ++i) {
        int c = c0 + ty + i * 8;
        out[((size_t)b * C + c) * F + f0 + tx] = tile[tx][ty + i * 8];
    }
}

// ----------------------------------------------------------------
extern "C" void kernel_launch(void* const* d_in, const int* in_sizes, int n_in,
                              void* d_out, int out_size, void* d_ws, size_t ws_size,
                              hipStream_t stream) {
    const size_t n = (size_t)NB * F * C;          // 589824
    float* cur  = (float*)d_ws;
    float* qh   = cur + n;
    float* sufM = qh + n;                         // [NB][F][H]
    float* sufL = sufM + (size_t)NB * F * H;
    float* sufA = sufL + (size_t)NB * F * H;      // [NB][F][H][16]
    float* wbuf = sufA + (size_t)NB * F * H * 16; // fp32 weights, 296193
    ushort_t* khT = (ushort_t*)(wbuf + 296193 + 3); // bf16 [mesh][ch][pos]
    ushort_t* vhT = khT + n;
    int* permIdx    = (int*)(vhT + n);
    int* invPerm    = permIdx + F;
    int* startOfPos = invPerm + F;
    int* ringStartD = startOfPos + F;
    int* flag       = ringStartD + NLV + 1;

    const int oWq = 0,       oWk = 16384,  oWv = 32768,  oWo = 49152;
    const int oW1 = 65536,   oB1 = 98304;
    const int oW2 = 98560,   oB2 = 164096;
    const int oW3 = 164352,  oB3 = 229888;
    const int oW4 = 230144,  oB4 = 295680;
    const int oW5 = 295936,  oB5 = 296192;
    const int wtot = 296193;

    WSegs segs = {{
        { d_in[1],  oWq, 16384 }, { d_in[2],  oWk, 16384 },
        { d_in[3],  oWv, 16384 }, { d_in[4],  oWo, 16384 },
        { d_in[5],  oW1, 32768 }, { d_in[6],  oB1, 256 },
        { d_in[7],  oW2, 65536 }, { d_in[8],  oB2, 256 },
        { d_in[9],  oW3, 65536 }, { d_in[10], oB3, 256 },
        { d_in[11], oW4, 65536 }, { d_in[12], oB4, 256 },
        { d_in[13], oW5, 256 },   { d_in[14], oB5, 1 },
    }};

    // host-side ring prefix (pure function of GRIDN; matches k_perm)
    int ringStart[NLV + 1];
    {
        int cnt[NLV];
        for (int l = 0; l < NLV; ++l) cnt[l] = 0;
        for (int i = 0; i < GRIDN; ++i)
            for (int j = 0; j < GRIDN; ++j)
                cnt[(i < 24 ? 24 - i : i - 24) + (j < 24 ? 24 - j : j - 24)]++;
        ringStart[0] = 0;
        for (int l = 0; l < NLV; ++l) ringStart[l + 1] = ringStart[l] + cnt[l];
    }

    float* out0 = (float*)d_out;                  // [B,C,F] fp32
    float* out1 = out0 + (size_t)NB * C * F;      // [B,F,1] fp32

    k_detect<<<1, 256, 0, stream>>>(d_in[0], flag);
    k_perm<<<1, 256, 0, stream>>>(permIdx, invPerm, startOfPos, ringStartD);
    k_convert<<<(wtot + 255) / 256, 256, 0, stream>>>(segs, flag, wbuf, wtot);
    k_transpose_in<<<dim3(F / 32, C / 32, NB), dim3(32, 8), 0, stream>>>(d_in[0], flag, cur);
    k_proj_init<<<(NB * F) / 8, 128, 0, stream>>>(cur, permIdx, wbuf + oWq, wbuf + oWk, wbuf + oWv,
                                                  qh, khT, vhT);
    k_suffix<<<NB * (F / 4), 256, 0, stream>>>(invPerm, startOfPos, qh, khT, vhT, sufM, sufL, sufA);

    for (int lv = 0; lv < NLV; ++lv) {
        int rs = ringStart[lv], re = ringStart[lv + 1];
        int nb = (re - rs + 3) / 4;
        k_level<<<2 * nb, 512, 0, stream>>>(rs, re, invPerm, qh, cur, khT, vhT,
                                            sufM, sufL, sufA,
                                            wbuf + oWk, wbuf + oWv, wbuf + oWo);
    }

    k_mlp<<<(NB * F) / 4, 256, 0, stream>>>(cur, wbuf + oW1, wbuf + oB1, wbuf + oW2, wbuf + oB2,
                                            wbuf + oW3, wbuf + oB3, wbuf + oW4, wbuf + oB4,
                                            wbuf + oW5, wbuf + oB5, out1);
    k_transpose_out<<<dim3(F / 32, C / 32, NB), dim3(32, 8), 0, stream>>>(cur, out0);
}

// Round 8
// 2336.970 us; speedup vs baseline: 1.8055x; 1.0499x over previous
//
#include <hip/hip_runtime.h>
#include <hip/hip_bf16.h>
#include <stdint.h>

#define GRIDN 48
#define F 2304
#define C 128
#define H 8
#define DH 16
#define NB 2          // batch (meshes)
#define WID 256
#define NLV 49        // BFS levels for GRID=48, anchor at (24,24)

#define NFB 144       // flood blocks (72 per mesh), all co-resident
#define NFBM 72       // flood blocks per mesh
#define NFT 512       // threads per flood block; 2 lanes (halves) per (q,h) state
#define QPB 32        // queries owned per block (pos = s*NFBM + bi)
#define MAXRING 96    // max BFS ring size (94) padded

typedef __hip_bfloat16 bf16;
typedef unsigned short ushort_t;

__device__ __forceinline__ float b2f(bf16 v) { return __bfloat162float(v); }

__device__ __forceinline__ ushort_t f2bu(float f) {
    __hip_bfloat16 b = __float2bfloat16(f);
    return *(ushort_t*)&b;
}

// unpack 4 bf16 (memory order) from uint2
__device__ __forceinline__ void unp4(uint2 u, float& a, float& b, float& c, float& d) {
    a = __uint_as_float(u.x << 16);
    b = __uint_as_float(u.x & 0xffff0000u);
    c = __uint_as_float(u.y << 16);
    d = __uint_as_float(u.y & 0xffff0000u);
}

// ---------------------------------------------------------------- K-1: input dtype detector
__global__ void k_detect(const void* __restrict__ x, int* __restrict__ flag) {
    __shared__ int bad;
    if (threadIdx.x == 0) bad = 0;
    __syncthreads();
    const bf16* xb = (const bf16*)x;
    int insane = 0;
    #pragma unroll
    for (int i = 0; i < 8; ++i) {
        float v = b2f(xb[threadIdx.x * 8 + i]);
        if (!(fabsf(v) < 1e10f)) insane = 1;
    }
    if (insane) atomicOr(&bad, 1);
    __syncthreads();
    if (threadIdx.x == 0) *flag = bad;
}

// ---------------------------------------------------------------- K0: ring permutation tables (+ zero barrier counter)
__global__ void k_perm(int* __restrict__ permIdx, int* __restrict__ invPerm,
                       int* __restrict__ startOfPos, int* __restrict__ ringStart,
                       int* __restrict__ gcount) {
    __shared__ int cnt[NLV], start[NLV], rs0[NLV];
    int t = threadIdx.x;
    if (t < NLV) cnt[t] = 0;
    if (t == 0) *gcount = 0;
    __syncthreads();
    for (int f = t; f < F; f += 256) {
        int d = abs(f / GRIDN - GRIDN / 2) + abs(f % GRIDN - GRIDN / 2);
        atomicAdd(&cnt[d], 1);
    }
    __syncthreads();
    if (t == 0) {
        int s = 0;
        for (int l = 0; l < NLV; ++l) { start[l] = s; rs0[l] = s; ringStart[l] = s; s += cnt[l]; }
        ringStart[NLV] = s;
    }
    __syncthreads();
    for (int f = t; f < F; f += 256) {
        int d = abs(f / GRIDN - GRIDN / 2) + abs(f % GRIDN - GRIDN / 2);
        int p = atomicAdd(&start[d], 1);
        permIdx[f] = p;
        invPerm[p] = f;
        startOfPos[p] = rs0[d];
    }
}

// ---------------------------------------------------------------- K0b: weights -> fp32
struct WSeg { const void* src; int off; int cnt; };
struct WSegs { WSeg s[14]; };

__global__ void k_convert(WSegs segs, const int* __restrict__ flag,
                          float* __restrict__ dst, int total) {
    int i = blockIdx.x * blockDim.x + threadIdx.x;
    if (i >= total) return;
    bool f32 = (*flag != 0);
    #pragma unroll 1
    for (int j = 0; j < 14; ++j) {
        int off = segs.s[j].off, cnt = segs.s[j].cnt;
        if (i >= off && i < off + cnt) {
            int k = i - off;
            dst[i] = f32 ? ((const float*)segs.s[j].src)[k]
                         : b2f(((const bf16*)segs.s[j].src)[k]);
            return;
        }
    }
}

// ---------------------------------------------------------------- K1: x[B,C,F] -> cur[B,F,C]
__global__ void k_transpose_in(const void* __restrict__ x, const int* __restrict__ flag,
                               float* __restrict__ cur) {
    __shared__ float tile[32][33];
    bool f32 = (*flag != 0);
    int b = blockIdx.z;
    int f0 = blockIdx.x * 32, c0 = blockIdx.y * 32;
    int tx = threadIdx.x, ty = threadIdx.y;
    #pragma unroll
    for (int i = 0; i < 4; ++i) {
        int c = c0 + ty + i * 8;
        size_t idx = ((size_t)b * C + c) * F + f0 + tx;
        tile[ty + i * 8][tx] = f32 ? ((const float*)x)[idx] : b2f(((const bf16*)x)[idx]);
    }
    __syncthreads();
    #pragma unroll
    for (int i = 0; i < 4; ++i) {
        int f = f0 + ty + i * 8;
        cur[((size_t)b * F + f) * C + c0 + tx] = tile[tx][ty + i * 8];
    }
}

// ---------------------------------------------------------------- K2: projections; khT/vhT bf16 [mesh][ch][pos]
__global__ __launch_bounds__(128) void k_proj_init(
        const float* __restrict__ cur, const int* __restrict__ permIdx,
        const float* __restrict__ Wq, const float* __restrict__ Wk, const float* __restrict__ Wv,
        float* __restrict__ qh, ushort_t* __restrict__ khT, ushort_t* __restrict__ vhT) {
    __shared__ float rows[8][C];
    int r0 = blockIdx.x * 8;
    int tid = threadIdx.x;
    #pragma unroll
    for (int r = 0; r < 8; ++r) rows[r][tid] = cur[(size_t)(r0 + r) * C + tid];
    __syncthreads();
    float aq[8], ak[8], av[8];
    #pragma unroll
    for (int r = 0; r < 8; ++r) { aq[r] = 0.f; ak[r] = 0.f; av[r] = 0.f; }
    for (int k = 0; k < C; ++k) {
        float wq = Wq[k * C + tid];
        float wk = Wk[k * C + tid];
        float wv = Wv[k * C + tid];
        #pragma unroll
        for (int r = 0; r < 8; ++r) {
            float xv = rows[r][k];
            aq[r] = fmaf(xv, wq, aq[r]);
            ak[r] = fmaf(xv, wk, ak[r]);
            av[r] = fmaf(xv, wv, av[r]);
        }
    }
    const float scale = 0.25f;
    #pragma unroll
    for (int r = 0; r < 8; ++r) {
        int grow = r0 + r;
        int mesh = grow / F, face = grow % F;
        int p = permIdx[face];
        qh[(size_t)grow * C + tid] = aq[r] * scale;
        khT[((size_t)mesh * C + tid) * F + p] = f2bu(ak[r]);
        vhT[((size_t)mesh * C + tid) * F + p] = f2bu(av[r]);
    }
}

// ---------------------------------------------------------------- K3a: suffix attention (initial K/V, bf16), 4 q/block
__global__ __launch_bounds__(256) void k_suffix(
        const int* __restrict__ invPerm, const int* __restrict__ startOfPos,
        const float* __restrict__ qh_all,
        const ushort_t* __restrict__ khT, const ushort_t* __restrict__ vhT,
        float* __restrict__ sufM, float* __restrict__ sufL, float* __restrict__ sufA) {
    int bx = blockIdx.x;
    int mesh = bx & 1;
    int p0 = (bx >> 1) * 4;
    int tid = threadIdx.x;
    __shared__ float sQh[4][C];
    __shared__ int sFace[4], sStart[4];
    if (tid < 4) {
        sFace[tid] = invPerm[p0 + tid];
        sStart[tid] = startOfPos[p0 + tid];
    }
    __syncthreads();
    {
        int j = tid >> 7, ch = tid & 127;
        sQh[j][ch]     = qh_all[((size_t)mesh * F + sFace[j]) * C + ch];
        sQh[j + 2][ch] = qh_all[((size_t)mesh * F + sFace[j + 2]) * C + ch];
    }
    __syncthreads();
    int head = tid >> 5, sub = tid & 31;
    float q[4][DH];
    #pragma unroll
    for (int j = 0; j < 4; ++j)
        #pragma unroll
        for (int d = 0; d < DH; ++d) q[j][d] = sQh[j][head * DH + d];
    const ushort_t* Kb = khT + ((size_t)mesh * C + head * DH) * F;
    const ushort_t* Vb = vhT + ((size_t)mesh * C + head * DH) * F;
    float m[4], l[4], acc[4][DH];
    #pragma unroll
    for (int j = 0; j < 4; ++j) {
        m[j] = -1e30f; l[j] = 0.f;
        #pragma unroll
        for (int d = 0; d < DH; ++d) acc[j][d] = 0.f;
    }
    int st0 = sStart[0], st1 = sStart[1], st2 = sStart[2], st3 = sStart[3];
    for (int base = st0 & ~127; base < F; base += 128) {
        int p4 = base + 4 * sub;
        float sc[4][4];
        #pragma unroll
        for (int j = 0; j < 4; ++j)
            #pragma unroll
            for (int c = 0; c < 4; ++c) sc[j][c] = 0.f;
        #pragma unroll
        for (int d = 0; d < DH; ++d) {
            uint2 u = *(const uint2*)(Kb + (size_t)d * F + p4);
            float kx, ky, kz, kw;
            unp4(u, kx, ky, kz, kw);
            #pragma unroll
            for (int j = 0; j < 4; ++j) {
                float a = q[j][d];
                sc[j][0] = fmaf(a, kx, sc[j][0]); sc[j][1] = fmaf(a, ky, sc[j][1]);
                sc[j][2] = fmaf(a, kz, sc[j][2]); sc[j][3] = fmaf(a, kw, sc[j][3]);
            }
        }
        #pragma unroll
        for (int c = 0; c < 4; ++c) {
            int pos = p4 + c;
            if (pos < st0) sc[0][c] = -1e30f;
            if (pos < st1) sc[1][c] = -1e30f;
            if (pos < st2) sc[2][c] = -1e30f;
            if (pos < st3) sc[3][c] = -1e30f;
        }
        float cj[4], px[4][4];
        #pragma unroll
        for (int j = 0; j < 4; ++j) {
            float mx = fmaxf(fmaxf(sc[j][0], sc[j][1]), fmaxf(sc[j][2], sc[j][3]));
            float mn = fmaxf(m[j], mx);
            cj[j] = __expf(m[j] - mn);
            px[j][0] = __expf(sc[j][0] - mn); px[j][1] = __expf(sc[j][1] - mn);
            px[j][2] = __expf(sc[j][2] - mn); px[j][3] = __expf(sc[j][3] - mn);
            l[j] = fmaf(l[j], cj[j], px[j][0] + px[j][1] + px[j][2] + px[j][3]);
            m[j] = mn;
        }
        #pragma unroll
        for (int d = 0; d < DH; ++d) {
            uint2 u = *(const uint2*)(Vb + (size_t)d * F + p4);
            float vx, vy, vz, vw;
            unp4(u, vx, vy, vz, vw);
            #pragma unroll
            for (int j = 0; j < 4; ++j) {
                float w = fmaf(px[j][0], vx, fmaf(px[j][1], vy, fmaf(px[j][2], vz, px[j][3] * vw)));
                acc[j][d] = fmaf(acc[j][d], cj[j], w);
            }
        }
    }
    #pragma unroll
    for (int w = 16; w >= 1; w >>= 1) {
        #pragma unroll
        for (int j = 0; j < 4; ++j) {
            float mo = __shfl_xor(m[j], w), lo = __shfl_xor(l[j], w);
            float mn = fmaxf(m[j], mo);
            float ca = __expf(m[j] - mn), cb = __expf(mo - mn);
            l[j] = l[j] * ca + lo * cb;
            #pragma unroll
            for (int d = 0; d < DH; ++d) {
                float ao = __shfl_xor(acc[j][d], w);
                acc[j][d] = acc[j][d] * ca + ao * cb;
            }
            m[j] = mn;
        }
    }
    if (sub == 0) {
        #pragma unroll
        for (int j = 0; j < 4; ++j) {
            size_t sb = ((size_t)mesh * F + p0 + j) * H + head;
            sufM[sb] = m[j];
            sufL[sb] = l[j];
            #pragma unroll
            for (int d = 0; d < DH; ++d) sufA[sb * 16 + d] = acc[j][d];
        }
    }
}

// ---------------------------------------------------------------- K3b: persistent push-flood (fixed r6)
// 144 blocks x 512 thr. Thread = (half, s, h): owns half the ring-keys of state
// (q = s*72+bi, h). State in registers (34 floats; launch_bounds(512,1) -> no spill).
// Cross-block comms: new K/V packed bf16 via agent-scope atomics (write-through, L2-bypass);
// staged once per level into LDS as fp32. Monotone-counter grid barrier (validated r6).
__global__ __launch_bounds__(NFT, 1) void k_flood3(
        const int* __restrict__ ringStart, const int* __restrict__ invPerm,
        const float* __restrict__ qh_all, float* __restrict__ cur,
        unsigned int* __restrict__ kvK, unsigned int* __restrict__ kvV,
        const float* __restrict__ sufM, const float* __restrict__ sufL,
        const float* __restrict__ sufA,
        const float* __restrict__ Wk, const float* __restrict__ Wv, const float* __restrict__ Wo,
        int* gcount) {
    __shared__ __align__(16) float sK[MAXRING * C];   // staged ring K (fp32)
    __shared__ __align__(16) float sV[MAXRING * C];
    __shared__ __align__(16) float sP[2][C];          // normalized attention out per finalized q
    __shared__ __align__(16) float sNew[2][C];        // new features per finalized q
    __shared__ float mrg[2][H][18];                   // half1 -> half0 state merge

    int bx = blockIdx.x, tid = threadIdx.x;
    int mesh = bx & 1, bi = bx >> 1;                  // bi in [0,72)
    int half = tid >> 8, r = tid & 255, s = r >> 3, h = r & 7;
    int pos = s * NFBM + bi;                          // owned sorted position
    int face = invPerm[pos];
    size_t qrow = ((size_t)mesh * F + face) * C + (h << 4);
    float qv[16];
    #pragma unroll
    for (int d = 0; d < 16; ++d) qv[d] = qh_all[qrow + d];
    float sm = -1e30f, sl = 0.f;
    float sacc[16];
    #pragma unroll
    for (int d = 0; d < 16; ++d) sacc[d] = 0.f;

    for (int lv = 0; lv < NLV; ++lv) {
        int rs = ringStart[lv], re = ringStart[lv + 1], ring = re - rs;

        // ---------- finalize owned queries in [rs, re)
        int s_min = (rs > bi) ? (rs - bi + NFBM - 1) / NFBM : 0;
        int s_max = (re - 1 >= bi) ? (re - 1 - bi) / NFBM : -1;
        int nf = s_max - s_min + 1;                   // block-uniform, <= 2
        bool fin = (pos >= rs) && (pos < re);
        if (nf > 0) {
            if (fin && half == 1) {
                float* p = mrg[s - s_min][h];
                p[0] = sm; p[1] = sl;
                #pragma unroll
                for (int d = 0; d < 16; ++d) p[2 + d] = sacc[d];
            }
            __syncthreads();
            if (fin && half == 0) {
                const float* p = mrg[s - s_min][h];
                float mo = p[0], lo = p[1];
                float mn = fmaxf(sm, mo);
                float ca = __expf(sm - mn), cb = __expf(mo - mn);
                float lm = sl * ca + lo * cb;
                float am[16];
                #pragma unroll
                for (int d = 0; d < 16; ++d) am[d] = sacc[d] * ca + p[2 + d] * cb;
                // merge suffix partial (initial K/V over [rs(q), F))
                size_t sb = ((size_t)mesh * F + pos) * H + h;
                float ms = sufM[sb], ls = sufL[sb];
                float mn2 = fmaxf(mn, ms);
                float e1 = __expf(mn - mn2), e2 = __expf(ms - mn2);
                float den = lm * e1 + ls * e2;
                float inv = 1.f / den;
                int slot = s - s_min;
                #pragma unroll
                for (int d = 0; d < 16; ++d)
                    sP[slot][(h << 4) + d] = (am[d] * e1 + sufA[sb * 16 + d] * e2) * inv;
            }
            __syncthreads();
            // Wo projection + residual
            for (int it = tid; it < nf * C; it += NFT) {
                int qq = it >> 7, ch = it & 127;
                int fpos = (s_min + qq) * NFBM + bi;
                int ff = invPerm[fpos];
                const float* pr = sP[qq];
                float o = 0.f;
                for (int k = 0; k < C; k += 4) {
                    float4 pv = *(const float4*)&pr[k];
                    o = fmaf(pv.x, Wo[(k + 0) * C + ch], o);
                    o = fmaf(pv.y, Wo[(k + 1) * C + ch], o);
                    o = fmaf(pv.z, Wo[(k + 2) * C + ch], o);
                    o = fmaf(pv.w, Wo[(k + 3) * C + ch], o);
                }
                size_t rw = ((size_t)mesh * F + ff) * C + ch;
                float nv = cur[rw] + o;
                cur[rw] = nv;
                sNew[qq][ch] = nv;
            }
            __syncthreads();
            // Wk/Wv projection -> packed-bf16 agent stores (pos-major)
            for (int it = tid; it < nf * 128; it += NFT) {   // 128 items/q: 64 K-pairs + 64 V-pairs
                int qq = it >> 7, cc = it & 127;
                bool isV = cc >= 64;
                int u = cc & 63, ch0 = u * 2;
                const float* W = isV ? Wv : Wk;
                const float* nr = sNew[qq];
                float a0 = 0.f, a1 = 0.f;
                for (int k = 0; k < C; k += 4) {
                    float4 pv = *(const float4*)&nr[k];
                    a0 = fmaf(pv.x, W[(k + 0) * C + ch0], a0);
                    a0 = fmaf(pv.y, W[(k + 1) * C + ch0], a0);
                    a0 = fmaf(pv.z, W[(k + 2) * C + ch0], a0);
                    a0 = fmaf(pv.w, W[(k + 3) * C + ch0], a0);
                    a1 = fmaf(pv.x, W[(k + 0) * C + ch0 + 1], a1);
                    a1 = fmaf(pv.y, W[(k + 1) * C + ch0 + 1], a1);
                    a1 = fmaf(pv.z, W[(k + 2) * C + ch0 + 1], a1);
                    a1 = fmaf(pv.w, W[(k + 3) * C + ch0 + 1], a1);
                }
                unsigned int pk = (unsigned int)f2bu(a0) | ((unsigned int)f2bu(a1) << 16);
                int fpos = (s_min + qq) * NFBM + bi;
                unsigned int* dst = (isV ? kvV : kvK) + ((size_t)mesh * F + fpos) * 64 + u;
                __hip_atomic_store(dst, pk, __ATOMIC_RELAXED, __HIP_MEMORY_SCOPE_AGENT);
            }
        }
        if (lv == NLV - 1) break;

        // ---------- grid barrier (syncthreads drains each thread's stores first)
        __syncthreads();
        if (tid == 0) {
            __hip_atomic_fetch_add(gcount, 1, __ATOMIC_RELAXED, __HIP_MEMORY_SCOPE_AGENT);
            int target = NFB * (lv + 1);
            while (__hip_atomic_load(gcount, __ATOMIC_RELAXED, __HIP_MEMORY_SCOPE_AGENT) < target)
                __builtin_amdgcn_s_sleep(2);
        }
        __syncthreads();

        // ---------- stage ring K/V (bf16 -> fp32 LDS), accumulate into pending states
        int maxPos = (QPB - 1) * NFBM + bi;
        if (maxPos >= re) {                           // block-uniform: any pending?
            for (int i = tid; i < ring * 64; i += NFT) {
                int kk = i >> 6, u = i & 63;
                size_t src = ((size_t)mesh * F + rs + kk) * 64 + u;
                unsigned int a = __hip_atomic_load(&kvK[src], __ATOMIC_RELAXED, __HIP_MEMORY_SCOPE_AGENT);
                unsigned int b = __hip_atomic_load(&kvV[src], __ATOMIC_RELAXED, __HIP_MEMORY_SCOPE_AGENT);
                sK[kk * C + 2 * u]     = __uint_as_float(a << 16);
                sK[kk * C + 2 * u + 1] = __uint_as_float(a & 0xffff0000u);
                sV[kk * C + 2 * u]     = __uint_as_float(b << 16);
                sV[kk * C + 2 * u + 1] = __uint_as_float(b & 0xffff0000u);
            }
            __syncthreads();
            if (pos >= re) {                          // pending states only
                int k0 = half ? (ring >> 1) : 0;
                int k1 = half ? ring : (ring >> 1);
                for (int kk = k0; kk < k1; ++kk) {
                    const float4* kp = (const float4*)&sK[kk * C + (h << 4)];
                    float4 a0 = kp[0], a1 = kp[1], a2 = kp[2], a3 = kp[3];
                    float sc = qv[0] * a0.x;
                    sc = fmaf(qv[1], a0.y, sc);  sc = fmaf(qv[2], a0.z, sc);  sc = fmaf(qv[3], a0.w, sc);
                    sc = fmaf(qv[4], a1.x, sc);  sc = fmaf(qv[5], a1.y, sc);  sc = fmaf(qv[6], a1.z, sc);
                    sc = fmaf(qv[7], a1.w, sc);  sc = fmaf(qv[8], a2.x, sc);  sc = fmaf(qv[9], a2.y, sc);
                    sc = fmaf(qv[10], a2.z, sc); sc = fmaf(qv[11], a2.w, sc); sc = fmaf(qv[12], a3.x, sc);
                    sc = fmaf(qv[13], a3.y, sc); sc = fmaf(qv[14], a3.z, sc); sc = fmaf(qv[15], a3.w, sc);
                    float mn = fmaxf(sm, sc);
                    float c = __expf(sm - mn), p = __expf(sc - mn);
                    sl = sl * c + p;
                    sm = mn;
                    const float4* vp = (const float4*)&sV[kk * C + (h << 4)];
                    float4 b0 = vp[0], b1 = vp[1], b2 = vp[2], b3 = vp[3];
                    sacc[0]  = sacc[0]  * c + p * b0.x;  sacc[1]  = sacc[1]  * c + p * b0.y;
                    sacc[2]  = sacc[2]  * c + p * b0.z;  sacc[3]  = sacc[3]  * c + p * b0.w;
                    sacc[4]  = sacc[4]  * c + p * b1.x;  sacc[5]  = sacc[5]  * c + p * b1.y;
                    sacc[6]  = sacc[6]  * c + p * b1.z;  sacc[7]  = sacc[7]  * c + p * b1.w;
                    sacc[8]  = sacc[8]  * c + p * b2.x;  sacc[9]  = sacc[9]  * c + p * b2.y;
                    sacc[10] = sacc[10] * c + p * b2.z;  sacc[11] = sacc[11] * c + p * b2.w;
                    sacc[12] = sacc[12] * c + p * b3.x;  sacc[13] = sacc[13] * c + p * b3.y;
                    sacc[14] = sacc[14] * c + p * b3.z;  sacc[15] = sacc[15] * c + p * b3.w;
                }
            }
        }
        // next level's barrier __syncthreads precedes any sK/sV overwrite
    }
}

// ---------------------------------------------------------------- K4: MLP + sigmoid, 4 rows/block
__global__ __launch_bounds__(256) void k_mlp(
        const float* __restrict__ cur,
        const float* __restrict__ W1, const float* __restrict__ b1,
        const float* __restrict__ W2, const float* __restrict__ b2,
        const float* __restrict__ W3, const float* __restrict__ b3,
        const float* __restrict__ W4, const float* __restrict__ b4,
        const float* __restrict__ W5, const float* __restrict__ b5,
        float* __restrict__ out_scores) {
    __shared__ __align__(16) float sIn[4][C];
    __shared__ __align__(16) float sA[4][WID];
    __shared__ __align__(16) float sB[4][WID];
    int tid = threadIdx.x;
    int r0 = blockIdx.x * 4;
    for (int i = tid; i < 4 * C; i += 256) sIn[i >> 7][i & 127] = cur[(size_t)r0 * C + i];
    __syncthreads();
    {
        float a[4];
        #pragma unroll
        for (int r = 0; r < 4; ++r) a[r] = 0.f;
        for (int k = 0; k < C; k += 4) {
            float w0 = W1[(k + 0) * WID + tid], w1 = W1[(k + 1) * WID + tid];
            float w2 = W1[(k + 2) * WID + tid], w3 = W1[(k + 3) * WID + tid];
            #pragma unroll
            for (int r = 0; r < 4; ++r) {
                float4 xv = *(const float4*)&sIn[r][k];
                a[r] = fmaf(xv.x, w0, fmaf(xv.y, w1, fmaf(xv.z, w2, fmaf(xv.w, w3, a[r]))));
            }
        }
        float bias = b1[tid];
        #pragma unroll
        for (int r = 0; r < 4; ++r) sA[r][tid] = fmaxf(a[r] + bias, 0.f);
    }
    __syncthreads();
    {
        float a[4];
        #pragma unroll
        for (int r = 0; r < 4; ++r) a[r] = 0.f;
        for (int k = 0; k < WID; k += 4) {
            float w0 = W2[(k + 0) * WID + tid], w1 = W2[(k + 1) * WID + tid];
            float w2 = W2[(k + 2) * WID + tid], w3 = W2[(k + 3) * WID + tid];
            #pragma unroll
            for (int r = 0; r < 4; ++r) {
                float4 xv = *(const float4*)&sA[r][k];
                a[r] = fmaf(xv.x, w0, fmaf(xv.y, w1, fmaf(xv.z, w2, fmaf(xv.w, w3, a[r]))));
            }
        }
        float bias = b2[tid];
        #pragma unroll
        for (int r = 0; r < 4; ++r) sB[r][tid] = fmaxf(a[r] + bias, 0.f);
    }
    __syncthreads();
    {
        float a[4];
        #pragma unroll
        for (int r = 0; r < 4; ++r) a[r] = 0.f;
        for (int k = 0; k < WID; k += 4) {
            float w0 = W3[(k + 0) * WID + tid], w1 = W3[(k + 1) * WID + tid];
            float w2 = W3[(k + 2) * WID + tid], w3 = W3[(k + 3) * WID + tid];
            #pragma unroll
            for (int r = 0; r < 4; ++r) {
                float4 xv = *(const float4*)&sB[r][k];
                a[r] = fmaf(xv.x, w0, fmaf(xv.y, w1, fmaf(xv.z, w2, fmaf(xv.w, w3, a[r]))));
            }
        }
        float bias = b3[tid];
        #pragma unroll
        for (int r = 0; r < 4; ++r) sA[r][tid] = fmaxf(a[r] + bias, 0.f);
    }
    __syncthreads();
    {
        float a[4];
        #pragma unroll
        for (int r = 0; r < 4; ++r) a[r] = 0.f;
        for (int k = 0; k < WID; k += 4) {
            float w0 = W4[(k + 0) * WID + tid], w1 = W4[(k + 1) * WID + tid];
            float w2 = W4[(k + 2) * WID + tid], w3 = W4[(k + 3) * WID + tid];
            #pragma unroll
            for (int r = 0; r < 4; ++r) {
                float4 xv = *(const float4*)&sA[r][k];
                a[r] = fmaf(xv.x, w0, fmaf(xv.y, w1, fmaf(xv.z, w2, fmaf(xv.w, w3, a[r]))));
            }
        }
        float bias = b4[tid];
        #pragma unroll
        for (int r = 0; r < 4; ++r) sB[r][tid] = fmaxf(a[r] + bias, 0.f);
    }
    __syncthreads();
    if (tid < 4) {
        float a = b5[0];
        for (int k = 0; k < WID; ++k) a = fmaf(sB[tid][k], W5[k], a);
        out_scores[r0 + tid] = 1.f / (1.f + __expf(-a));
    }
}

// ---------------------------------------------------------------- K5: cur[B,F,C] -> out0[B,C,F]
__global__ void k_transpose_out(const float* __restrict__ cur, float* __restrict__ out) {
    __shared__ float tile[32][33];
    int b = blockIdx.z;
    int f0 = blockIdx.x * 32, c0 = blockIdx.y * 32;
    int tx = threadIdx.x, ty = threadIdx.y;
    #pragma unroll
    for (int i = 0; i < 4; ++i) {
        int f = f0 + ty + i * 8;
        tile[ty + i * 8][tx] = cur[((size_t)b * F + f) * C + c0 + tx];
    }
    __syncthreads();
    #pragma unroll
    for (int i = 0; i < 4; ++i) {
        int c = c0 + ty + i * 8;
        out[((size_t)b * C + c) * F + f0 + tx] = tile[tx][ty + i * 8];
    }
}

// ----------------------------------------------------------------
extern "C" void kernel_launch(void* const* d_in, const int* in_sizes, int n_in,
                              void* d_out, int out_size, void* d_ws, size_t ws_size,
                              hipStream_t stream) {
    const size_t n = (size_t)NB * F * C;          // 589824
    float* cur  = (float*)d_ws;
    float* qh   = cur + n;
    float* sufM = qh + n;                         // [NB][F][H]
    float* sufL = sufM + (size_t)NB * F * H;
    float* sufA = sufL + (size_t)NB * F * H;      // [NB][F][H][16]
    float* wbuf = sufA + (size_t)NB * F * H * 16; // fp32 weights, 296193
    ushort_t* khT = (ushort_t*)(wbuf + 296193 + 3); // bf16 [mesh][ch][pos]
    ushort_t* vhT = khT + n;
    unsigned int* kvK = (unsigned int*)(vhT + n); // packed bf16 [mesh][pos][64]
    unsigned int* kvV = kvK + (size_t)NB * F * 64;
    int* permIdx    = (int*)(kvV + (size_t)NB * F * 64);
    int* invPerm    = permIdx + F;
    int* startOfPos = invPerm + F;
    int* ringStartD = startOfPos + F;
    int* flag       = ringStartD + NLV + 1;
    int* gcount     = flag + 1;

    const int oWq = 0,       oWk = 16384,  oWv = 32768,  oWo = 49152;
    const int oW1 = 65536,   oB1 = 98304;
    const int oW2 = 98560,   oB2 = 164096;
    const int oW3 = 164352,  oB3 = 229888;
    const int oW4 = 230144,  oB4 = 295680;
    const int oW5 = 295936,  oB5 = 296192;
    const int wtot = 296193;

    WSegs segs = {{
        { d_in[1],  oWq, 16384 }, { d_in[2],  oWk, 16384 },
        { d_in[3],  oWv, 16384 }, { d_in[4],  oWo, 16384 },
        { d_in[5],  oW1, 32768 }, { d_in[6],  oB1, 256 },
        { d_in[7],  oW2, 65536 }, { d_in[8],  oB2, 256 },
        { d_in[9],  oW3, 65536 }, { d_in[10], oB3, 256 },
        { d_in[11], oW4, 65536 }, { d_in[12], oB4, 256 },
        { d_in[13], oW5, 256 },   { d_in[14], oB5, 1 },
    }};

    float* out0 = (float*)d_out;                  // [B,C,F] fp32
    float* out1 = out0 + (size_t)NB * C * F;      // [B,F,1] fp32

    k_detect<<<1, 256, 0, stream>>>(d_in[0], flag);
    k_perm<<<1, 256, 0, stream>>>(permIdx, invPerm, startOfPos, ringStartD, gcount);
    k_convert<<<(wtot + 255) / 256, 256, 0, stream>>>(segs, flag, wbuf, wtot);
    k_transpose_in<<<dim3(F / 32, C / 32, NB), dim3(32, 8), 0, stream>>>(d_in[0], flag, cur);
    k_proj_init<<<(NB * F) / 8, 128, 0, stream>>>(cur, permIdx, wbuf + oWq, wbuf + oWk, wbuf + oWv,
                                                  qh, khT, vhT);
    k_suffix<<<NB * (F / 4), 256, 0, stream>>>(invPerm, startOfPos, qh, khT, vhT, sufM, sufL, sufA);
    k_flood3<<<NFB, NFT, 0, stream>>>(ringStartD, invPerm, qh, cur, kvK, kvV,
                                      sufM, sufL, sufA,
                                      wbuf + oWk, wbuf + oWv, wbuf + oWo, gcount);
    k_mlp<<<(NB * F) / 4, 256, 0, stream>>>(cur, wbuf + oW1, wbuf + oB1, wbuf + oW2, wbuf + oB2,
                                            wbuf + oW3, wbuf + oB3, wbuf + oW4, wbuf + oB4,
                                            wbuf + oW5, wbuf + oB5, out1);
    k_transpose_out<<<dim3(F / 32, C / 32, NB), dim3(32, 8), 0, stream>>>(cur, out0);
}